// Round 7
// baseline (624.814 us; speedup 1.0000x reference)
//
#include <hip/hip_runtime.h>
#include <hip/hip_fp16.h>
#include <math.h>

#define N_NODES 100000
#define N_EDGES 1600000
#define ETOT    (N_EDGES + N_NODES)
#define NHEAD   4
#define ED      8

// ---------------- CSR build ----------------

__global__ void count_kernel(const int* __restrict__ ei, int* __restrict__ counts) {
    int e = blockIdx.x * 256 + threadIdx.x;
    if (e >= ETOT) return;
    int d = (e < N_EDGES) ? ei[N_EDGES + e] : (e - N_EDGES);
    atomicAdd(&counts[d], 1);
}

#define SCAN_CHUNK 1024
#define SCAN_NB    ((N_NODES + SCAN_CHUNK - 1) / SCAN_CHUNK)   // 98

__global__ void scan1_kernel(const int* __restrict__ counts, int* __restrict__ rowptr,
                             int* __restrict__ bsum) {
    __shared__ int tmp[SCAN_CHUNK];
    int t = threadIdx.x;
    int i = blockIdx.x * SCAN_CHUNK + t;
    int v = (i < N_NODES) ? counts[i] : 0;
    tmp[t] = v;
    __syncthreads();
    for (int off = 1; off < SCAN_CHUNK; off <<= 1) {
        int x = (t >= off) ? tmp[t - off] : 0;
        __syncthreads();
        tmp[t] += x;
        __syncthreads();
    }
    if (i < N_NODES) rowptr[i] = tmp[t] - v;
    if (t == SCAN_CHUNK - 1) bsum[blockIdx.x] = tmp[t];
}

__global__ void scan2_kernel(int* __restrict__ bsum) {
    if (threadIdx.x == 0 && blockIdx.x == 0) {
        int run = 0;
        for (int b = 0; b < SCAN_NB; ++b) { int t = bsum[b]; bsum[b] = run; run += t; }
    }
}

__global__ void scan3_kernel(int* __restrict__ rowptr, const int* __restrict__ bsum,
                             int* __restrict__ cursor) {
    int i = blockIdx.x * SCAN_CHUNK + threadIdx.x;
    if (i < N_NODES) {
        int v = rowptr[i] + bsum[blockIdx.x];
        rowptr[i] = v;
        cursor[i] = v;
    }
    if (i == 0) rowptr[N_NODES] = ETOT;
}

// ---------------- fold We/a_edge into M[8][4] ----------------

__global__ void make_M(const float* __restrict__ We, const float* __restrict__ a_edge,
                       float* __restrict__ M, int C) {
    int t = threadIdx.x;
    if (t >= ED * NHEAD) return;
    int d = t >> 2, h = t & 3;
    float s = 0.f;
    for (int c = 0; c < C; ++c) s += We[d * (NHEAD * C) + h * C + c] * a_edge[h * C + c];
    M[d * NHEAD + h] = s;
}

// ---------------- fill: ONE 32B scatter per edge carrying src + ae for BOTH layers --
// record layout (32B): [0:4) src | [4:12) ae1 as 4xfp16 | [12:20) ae2 as 4xfp16 | pad

__global__ __launch_bounds__(256) void fill_kernel(
    const int* __restrict__ ei, const float* __restrict__ ea,
    const float* __restrict__ M1, const float* __restrict__ M2,
    int* __restrict__ cursor, uint* __restrict__ rec) {
    int e = blockIdx.x * 256 + threadIdx.x;
    if (e >= ETOT) return;
    int s, d;
    float a10 = 0, a11 = 0, a12 = 0, a13 = 0;
    float a20 = 0, a21 = 0, a22 = 0, a23 = 0;
    if (e < N_EDGES) {
        s = ei[e]; d = ei[N_EDGES + e];
        const float* er = ea + (size_t)e * ED;
        float4 E0 = *reinterpret_cast<const float4*>(er);
        float4 E1 = *reinterpret_cast<const float4*>(er + 4);
        float ev[8] = {E0.x, E0.y, E0.z, E0.w, E1.x, E1.y, E1.z, E1.w};
#pragma unroll
        for (int dd = 0; dd < 8; ++dd) {
            float xv = ev[dd];
            a10 += xv * M1[dd * 4 + 0]; a11 += xv * M1[dd * 4 + 1];
            a12 += xv * M1[dd * 4 + 2]; a13 += xv * M1[dd * 4 + 3];
            a20 += xv * M2[dd * 4 + 0]; a21 += xv * M2[dd * 4 + 1];
            a22 += xv * M2[dd * 4 + 2]; a23 += xv * M2[dd * 4 + 3];
        }
    } else {
        s = e - N_EDGES; d = s;     // self-loop: edge_attr = 0 -> ae = 0
    }
    int p = atomicAdd(&cursor[d], 1);
    __half2 h10 = __floats2half2_rn(a10, a11);
    __half2 h11 = __floats2half2_rn(a12, a13);
    __half2 h20 = __floats2half2_rn(a20, a21);
    __half2 h21 = __floats2half2_rn(a22, a23);
    uint4 lo;
    lo.x = (uint)s;
    lo.y = *reinterpret_cast<uint*>(&h10);
    lo.z = *reinterpret_cast<uint*>(&h11);
    lo.w = *reinterpret_cast<uint*>(&h20);
    uint* rp = rec + (size_t)p * 8;
    *reinterpret_cast<uint4*>(rp) = lo;
    rp[4] = *reinterpret_cast<uint*>(&h21);
}

// ---------------- h = x @ W + per-node attention scalars ----------------
// Register-blocked over 4 nodes: one W float4 feeds 16 FMAs (4x less L1 traffic
// than 1 node/thread). x staged in LDS, rows padded +4 floats (16B-aligned, and
// bank stride 68/36 banks -> conflict-free b128 reads).

template <int FIN, int C>
__global__ __launch_bounds__(256) void feat_kernel(
    const float* __restrict__ x, const float* __restrict__ W,
    const float* __restrict__ a_src, const float* __restrict__ a_dst,
    __half* __restrict__ h, float* __restrict__ as_n, float* __restrict__ ad_n) {
    constexpr int CH  = NHEAD * C;
    constexpr int TPN = CH / 4;        // threads per node-group (== C)
    constexpr int NG  = 256 / TPN;     // node-groups per block
    constexpr int NPB = NG * 4;        // nodes per block (32 / 64)
    __shared__ float xs[NPB][FIN + 4];
    int t = threadIdx.x;
    int nbase = blockIdx.x * NPB;
    for (int i = t; i < NPB * FIN; i += 256) {
        int nn = i / FIN, dd = i % FIN;
        int gn = nbase + nn;
        xs[nn][dd] = (gn < N_NODES) ? x[(size_t)gn * FIN + dd] : 0.f;
    }
    __syncthreads();
    int ng = t / TPN;
    int ct = t % TPN;
    int n0 = nbase + ng * 4;

    float acc[4][4];
#pragma unroll
    for (int j = 0; j < 4; ++j)
#pragma unroll
        for (int k = 0; k < 4; ++k) acc[j][k] = 0.f;

    const float* wp = W + ct * 4;
#pragma unroll
    for (int dd = 0; dd < FIN; dd += 4) {
        float4 xv[4];
#pragma unroll
        for (int j = 0; j < 4; ++j)
            xv[j] = *reinterpret_cast<const float4*>(&xs[ng * 4 + j][dd]);
#pragma unroll
        for (int k = 0; k < 4; ++k) {
            float4 wv = *reinterpret_cast<const float4*>(wp + (size_t)(dd + k) * CH);
            float xk[4] = {k == 0 ? xv[0].x : k == 1 ? xv[0].y : k == 2 ? xv[0].z : xv[0].w,
                           k == 0 ? xv[1].x : k == 1 ? xv[1].y : k == 2 ? xv[1].z : xv[1].w,
                           k == 0 ? xv[2].x : k == 1 ? xv[2].y : k == 2 ? xv[2].z : xv[2].w,
                           k == 0 ? xv[3].x : k == 1 ? xv[3].y : k == 2 ? xv[3].z : xv[3].w};
#pragma unroll
            for (int j = 0; j < 4; ++j) {
                acc[j][0] += xk[j] * wv.x;
                acc[j][1] += xk[j] * wv.y;
                acc[j][2] += xk[j] * wv.z;
                acc[j][3] += xk[j] * wv.w;
            }
        }
    }

    int c4 = ct * 4;
    float4 asv = *reinterpret_cast<const float4*>(a_src + c4);
    float4 adv = *reinterpret_cast<const float4*>(a_dst + c4);
    constexpr int GRP = C / 4;          // threads covering one head
    int head = ct / GRP;
#pragma unroll
    for (int j = 0; j < 4; ++j) {
        int n = n0 + j;
        bool ok = n < N_NODES;
        if (ok) {
            __half2 p01 = __floats2half2_rn(acc[j][0], acc[j][1]);
            __half2 p23 = __floats2half2_rn(acc[j][2], acc[j][3]);
            uint2 u;
            u.x = *reinterpret_cast<uint*>(&p01);
            u.y = *reinterpret_cast<uint*>(&p23);
            *reinterpret_cast<uint2*>(reinterpret_cast<__half*>(h) + (size_t)n * CH + c4) = u;
        }
        float sa = acc[j][0] * asv.x + acc[j][1] * asv.y + acc[j][2] * asv.z + acc[j][3] * asv.w;
        float sd = acc[j][0] * adv.x + acc[j][1] * adv.y + acc[j][2] * adv.z + acc[j][3] * adv.w;
#pragma unroll
        for (int off = GRP / 2; off > 0; off >>= 1) {
            sa += __shfl_xor(sa, off);
            sd += __shfl_xor(sd, off);
        }
        if (ok && (ct & (GRP - 1)) == 0) {
            as_n[(size_t)n * NHEAD + head] = sa;
            ad_n[(size_t)n * NHEAD + head] = sd;
        }
    }
}

// ---------------- fused aggregation: one wave per dst node ----------------
// Per edge: 32B record (p-sequential), 4B as_n gather, h-row gather,
// w = exp(leaky(as+ad+ae)); predicated unroll-8 keeps 8 chains in flight.

template <int C, int AEOFF>
__global__ __launch_bounds__(256) void gat_agg(
    const int* __restrict__ rowptr, const char* __restrict__ rec,
    const __half* __restrict__ hbuf, const float* __restrict__ as_n,
    const float* __restrict__ ad_n, const float* __restrict__ bias,
    float* __restrict__ out) {
    constexpr int FPL = (NHEAD * C) / 64;   // 2 (C=32) or 1 (C=16)
    int lane = threadIdx.x & 63;
    int n = blockIdx.x * 4 + (threadIdx.x >> 6);
    if (n >= N_NODES) return;
    int head = lane >> 4;

    float ad = ad_n[(size_t)n * NHEAD + head];
    const __half2* h2p = reinterpret_cast<const __half2*>(hbuf);

    int p0 = __builtin_amdgcn_readfirstlane(rowptr[n]);
    int p1 = __builtin_amdgcn_readfirstlane(rowptr[n + 1]);

    float acc[8][FPL];
    float den[8];
#pragma unroll
    for (int j = 0; j < 8; ++j) {
        den[j] = 0.f;
#pragma unroll
        for (int k = 0; k < FPL; ++k) acc[j][k] = 0.f;
    }

    for (int p = p0; p < p1; p += 8) {
        int   sp[8];
        float w[8];
#pragma unroll
        for (int j = 0; j < 8; ++j) {
            int pp = p + j;
            bool ok = pp < p1;
            int q = ok ? pp : (p1 - 1);
            const char* rp = rec + (size_t)q * 32;
            sp[j] = *reinterpret_cast<const int*>(rp);
            __half aeh = *reinterpret_cast<const __half*>(rp + AEOFF + 2 * head);
            float a = as_n[(size_t)sp[j] * NHEAD + head] + ad + __half2float(aeh);
            a = (a > 0.f) ? a : 0.2f * a;
            float wv = __expf(a);
            w[j] = ok ? wv : 0.f;
        }
#pragma unroll
        for (int j = 0; j < 8; ++j) {
            float v[FPL];
            if constexpr (C == 32) {
                float2 f = __half22float2(h2p[(size_t)sp[j] * 64 + lane]);
                v[0] = f.x; v[1] = f.y;
            } else {
                v[0] = __half2float(hbuf[(size_t)sp[j] * 64 + lane]);
            }
            den[j] += w[j];
#pragma unroll
            for (int k = 0; k < FPL; ++k) acc[j][k] += w[j] * v[k];
        }
    }

    float dsum = ((den[0] + den[1]) + (den[2] + den[3]))
               + ((den[4] + den[5]) + (den[6] + den[7]));
    float inv = 1.f / (dsum + 1e-16f);
    float v[FPL];
#pragma unroll
    for (int k = 0; k < FPL; ++k) {
        float a = ((acc[0][k] + acc[1][k]) + (acc[2][k] + acc[3][k]))
                + ((acc[4][k] + acc[5][k]) + (acc[6][k] + acc[7][k]));
        v[k] = a * inv;
    }
    // head mean: lanes l, l^16, l^32, l^48 hold the same within-head column
#pragma unroll
    for (int k = 0; k < FPL; ++k) {
        v[k] += __shfl_xor(v[k], 16);
        v[k] += __shfl_xor(v[k], 32);
    }
    if (lane < 16) {
#pragma unroll
        for (int k = 0; k < FPL; ++k) {
            int c = lane * FPL + k;
            float o = 0.25f * v[k] + bias[c];
            o = (o > 0.f) ? o : expm1f(o);
            out[(size_t)n * C + c] = o;
        }
    }
}

// ---------------- launch ----------------

static inline size_t align_up(size_t x, size_t a) { return (x + a - 1) & ~(a - 1); }

extern "C" void kernel_launch(void* const* d_in, const int* in_sizes, int n_in,
                              void* d_out, int out_size, void* d_ws, size_t ws_size,
                              hipStream_t stream) {
    const float* x       = (const float*)d_in[0];
    const int*   ei      = (const int*)d_in[1];
    const float* ea      = (const float*)d_in[2];
    const float* W1      = (const float*)d_in[3];
    const float* We1     = (const float*)d_in[4];
    const float* a_src1  = (const float*)d_in[5];
    const float* a_dst1  = (const float*)d_in[6];
    const float* a_edge1 = (const float*)d_in[7];
    const float* b1      = (const float*)d_in[8];
    const float* W2      = (const float*)d_in[9];
    const float* We2     = (const float*)d_in[10];
    const float* a_src2  = (const float*)d_in[11];
    const float* a_dst2  = (const float*)d_in[12];
    const float* a_edge2 = (const float*)d_in[13];
    const float* b2      = (const float*)d_in[14];
    float* out = (float*)d_out;

    char* p = (char*)d_ws;
    auto take = [&](size_t bytes) { char* r = p; p += align_up(bytes, 256); return r; };
    int*   counts = (int*)take(sizeof(int) * N_NODES);
    int*   rowptr = (int*)take(sizeof(int) * (N_NODES + 1));
    int*   cursor = (int*)take(sizeof(int) * N_NODES);
    int*   bsum   = (int*)take(sizeof(int) * 128);
    char*  rec    = (char*)take((size_t)ETOT * 32);             // 54.4 MB
    float* as_n   = (float*)take(sizeof(float) * N_NODES * NHEAD);
    float* ad_n   = (float*)take(sizeof(float) * N_NODES * NHEAD);
    __half* hbuf  = (__half*)take((size_t)N_NODES * 128 * 2);   // 25.6 MB
    float* x2     = (float*)take(sizeof(float) * (size_t)N_NODES * 32);
    float* M1     = (float*)take(sizeof(float) * ED * NHEAD);
    float* M2     = (float*)take(sizeof(float) * ED * NHEAD);

    hipMemsetAsync(counts, 0, sizeof(int) * N_NODES, stream);

    int egrid = (ETOT + 255) / 256;
    count_kernel<<<egrid, 256, 0, stream>>>(ei, counts);
    scan1_kernel<<<SCAN_NB, SCAN_CHUNK, 0, stream>>>(counts, rowptr, bsum);
    scan2_kernel<<<1, 1, 0, stream>>>(bsum);
    scan3_kernel<<<SCAN_NB, SCAN_CHUNK, 0, stream>>>(rowptr, bsum, cursor);

    make_M<<<1, 32, 0, stream>>>(We1, a_edge1, M1, 32);
    make_M<<<1, 32, 0, stream>>>(We2, a_edge2, M2, 16);

    fill_kernel<<<egrid, 256, 0, stream>>>(ei, ea, M1, M2, cursor, (uint*)rec);

    int ngrid = N_NODES / 4;   // 25000

    // ---- layer 1: Fin=64, C=32 (32 nodes/block), h fp16 ----
    feat_kernel<64, 32><<<(N_NODES + 31) / 32, 256, 0, stream>>>(
        x, W1, a_src1, a_dst1, hbuf, as_n, ad_n);
    gat_agg<32, 4><<<ngrid, 256, 0, stream>>>(rowptr, rec, hbuf, as_n, ad_n, b1, x2);

    // ---- layer 2: Fin=32, C=16 (64 nodes/block), h fp16 ----
    feat_kernel<32, 16><<<(N_NODES + 63) / 64, 256, 0, stream>>>(
        x2, W2, a_src2, a_dst2, hbuf, as_n, ad_n);
    gat_agg<16, 12><<<ngrid, 256, 0, stream>>>(rowptr, rec, hbuf, as_n, ad_n, b2, out);
}

// Round 9
// 532.689 us; speedup vs baseline: 1.1729x; 1.1729x over previous
//
#include <hip/hip_runtime.h>
#include <hip/hip_fp16.h>
#include <math.h>

#define N_NODES 100000
#define N_EDGES 1600000
#define ETOT    (N_EDGES + N_NODES)
#define NHEAD   4
#define ED      8

// ---------------- CSR build ----------------

__global__ void count_kernel(const int* __restrict__ ei, int* __restrict__ counts) {
    int e = blockIdx.x * 256 + threadIdx.x;
    if (e >= ETOT) return;
    int d = (e < N_EDGES) ? ei[N_EDGES + e] : (e - N_EDGES);
    atomicAdd(&counts[d], 1);
}

#define SCAN_CHUNK 1024
#define SCAN_NB    ((N_NODES + SCAN_CHUNK - 1) / SCAN_CHUNK)   // 98

__global__ void scan1_kernel(const int* __restrict__ counts, int* __restrict__ rowptr,
                             int* __restrict__ bsum) {
    __shared__ int tmp[SCAN_CHUNK];
    int t = threadIdx.x;
    int i = blockIdx.x * SCAN_CHUNK + t;
    int v = (i < N_NODES) ? counts[i] : 0;
    tmp[t] = v;
    __syncthreads();
    for (int off = 1; off < SCAN_CHUNK; off <<= 1) {
        int x = (t >= off) ? tmp[t - off] : 0;
        __syncthreads();
        tmp[t] += x;
        __syncthreads();
    }
    if (i < N_NODES) rowptr[i] = tmp[t] - v;
    if (t == SCAN_CHUNK - 1) bsum[blockIdx.x] = tmp[t];
}

__global__ void scan2_kernel(int* __restrict__ bsum) {
    if (threadIdx.x == 0 && blockIdx.x == 0) {
        int run = 0;
        for (int b = 0; b < SCAN_NB; ++b) { int t = bsum[b]; bsum[b] = run; run += t; }
    }
}

__global__ void scan3_kernel(int* __restrict__ rowptr, const int* __restrict__ bsum,
                             int* __restrict__ cursor) {
    int i = blockIdx.x * SCAN_CHUNK + threadIdx.x;
    if (i < N_NODES) {
        int v = rowptr[i] + bsum[blockIdx.x];
        rowptr[i] = v;
        cursor[i] = v;
    }
    if (i == 0) rowptr[N_NODES] = ETOT;
}

// ---------------- fold We/a_edge into M[8][4] ----------------

__global__ void make_M(const float* __restrict__ We, const float* __restrict__ a_edge,
                       float* __restrict__ M, int C) {
    int t = threadIdx.x;
    if (t >= ED * NHEAD) return;
    int d = t >> 2, h = t & 3;
    float s = 0.f;
    for (int c = 0; c < C; ++c) s += We[d * (NHEAD * C) + h * C + c] * a_edge[h * C + c];
    M[d * NHEAD + h] = s;
}

// ---------------- fill: ONE 32B scatter per edge carrying src + ae for BOTH layers --
// record layout (32B): [0:4) src | [4:12) ae1 as 4xfp16 | [12:20) ae2 as 4xfp16 | pad

__global__ __launch_bounds__(256) void fill_kernel(
    const int* __restrict__ ei, const float* __restrict__ ea,
    const float* __restrict__ M1, const float* __restrict__ M2,
    int* __restrict__ cursor, uint* __restrict__ rec) {
    int e = blockIdx.x * 256 + threadIdx.x;
    if (e >= ETOT) return;
    int s, d;
    float a10 = 0, a11 = 0, a12 = 0, a13 = 0;
    float a20 = 0, a21 = 0, a22 = 0, a23 = 0;
    if (e < N_EDGES) {
        s = ei[e]; d = ei[N_EDGES + e];
        const float* er = ea + (size_t)e * ED;
        float4 E0 = *reinterpret_cast<const float4*>(er);
        float4 E1 = *reinterpret_cast<const float4*>(er + 4);
        float ev[8] = {E0.x, E0.y, E0.z, E0.w, E1.x, E1.y, E1.z, E1.w};
#pragma unroll
        for (int dd = 0; dd < 8; ++dd) {
            float xv = ev[dd];
            a10 += xv * M1[dd * 4 + 0]; a11 += xv * M1[dd * 4 + 1];
            a12 += xv * M1[dd * 4 + 2]; a13 += xv * M1[dd * 4 + 3];
            a20 += xv * M2[dd * 4 + 0]; a21 += xv * M2[dd * 4 + 1];
            a22 += xv * M2[dd * 4 + 2]; a23 += xv * M2[dd * 4 + 3];
        }
    } else {
        s = e - N_EDGES; d = s;     // self-loop: edge_attr = 0 -> ae = 0
    }
    int p = atomicAdd(&cursor[d], 1);
    __half2 h10 = __floats2half2_rn(a10, a11);
    __half2 h11 = __floats2half2_rn(a12, a13);
    __half2 h20 = __floats2half2_rn(a20, a21);
    __half2 h21 = __floats2half2_rn(a22, a23);
    uint4 lo;
    lo.x = (uint)s;
    lo.y = *reinterpret_cast<uint*>(&h10);
    lo.z = *reinterpret_cast<uint*>(&h11);
    lo.w = *reinterpret_cast<uint*>(&h20);
    uint* rp = rec + (size_t)p * 8;
    *reinterpret_cast<uint4*>(rp) = lo;
    rp[4] = *reinterpret_cast<uint*>(&h21);
}

// ---------------- h = x @ W + per-node attention scalars ----------------
// 4-node register blocking (one W float4 -> 16 FMAs), W AND x staged in LDS,
// VGPR capped at 128 via __launch_bounds__(256,4), dd-loop unroll limited to 2.

template <int FIN, int C>
__global__ __launch_bounds__(256, 4) void feat_kernel(
    const float* __restrict__ x, const float* __restrict__ W,
    const float* __restrict__ a_src, const float* __restrict__ a_dst,
    __half* __restrict__ h, float* __restrict__ as_n, float* __restrict__ ad_n) {
    constexpr int CH  = NHEAD * C;
    constexpr int TPN = C;             // threads per node-group (4 channels each)
    constexpr int NG  = 256 / TPN;     // node-groups per block
    constexpr int NPB = NG * 4;        // nodes per block (32 / 64)
    __shared__ float xs[NPB][FIN + 4];
    __shared__ float ws[FIN][CH];
    int t = threadIdx.x;
    int nbase = blockIdx.x * NPB;
    // stage W (coalesced)
    for (int i = t; i < FIN * CH; i += 256) ((float*)ws)[i] = W[i];
    // stage x (coalesced)
    for (int i = t; i < NPB * FIN; i += 256) {
        int nn = i / FIN, dd = i % FIN;
        int gn = nbase + nn;
        xs[nn][dd] = (gn < N_NODES) ? x[(size_t)gn * FIN + dd] : 0.f;
    }
    __syncthreads();
    int ng = t / TPN;
    int ct = t % TPN;
    int c4 = ct * 4;
    int n0 = nbase + ng * 4;

    float acc[4][4];
#pragma unroll
    for (int j = 0; j < 4; ++j)
#pragma unroll
        for (int k = 0; k < 4; ++k) acc[j][k] = 0.f;

#pragma unroll 2
    for (int dd = 0; dd < FIN; dd += 4) {
        float4 wv[4];
#pragma unroll
        for (int k = 0; k < 4; ++k)
            wv[k] = *reinterpret_cast<const float4*>(&ws[dd + k][c4]);
#pragma unroll
        for (int j = 0; j < 4; ++j) {
            float4 xv = *reinterpret_cast<const float4*>(&xs[ng * 4 + j][dd]);
            acc[j][0] += xv.x * wv[0].x + xv.y * wv[1].x + xv.z * wv[2].x + xv.w * wv[3].x;
            acc[j][1] += xv.x * wv[0].y + xv.y * wv[1].y + xv.z * wv[2].y + xv.w * wv[3].y;
            acc[j][2] += xv.x * wv[0].z + xv.y * wv[1].z + xv.z * wv[2].z + xv.w * wv[3].z;
            acc[j][3] += xv.x * wv[0].w + xv.y * wv[1].w + xv.z * wv[2].w + xv.w * wv[3].w;
        }
    }

    float4 asv = *reinterpret_cast<const float4*>(a_src + c4);
    float4 adv = *reinterpret_cast<const float4*>(a_dst + c4);
    constexpr int GRP = C / 4;          // threads covering one head
    int head = ct / GRP;
#pragma unroll
    for (int j = 0; j < 4; ++j) {
        int n = n0 + j;
        bool ok = n < N_NODES;
        if (ok) {
            __half2 p01 = __floats2half2_rn(acc[j][0], acc[j][1]);
            __half2 p23 = __floats2half2_rn(acc[j][2], acc[j][3]);
            uint2 u;
            u.x = *reinterpret_cast<uint*>(&p01);
            u.y = *reinterpret_cast<uint*>(&p23);
            *reinterpret_cast<uint2*>(h + (size_t)n * CH + c4) = u;
        }
        float sa = acc[j][0] * asv.x + acc[j][1] * asv.y + acc[j][2] * asv.z + acc[j][3] * asv.w;
        float sd = acc[j][0] * adv.x + acc[j][1] * adv.y + acc[j][2] * adv.z + acc[j][3] * adv.w;
#pragma unroll
        for (int off = GRP / 2; off > 0; off >>= 1) {
            sa += __shfl_xor(sa, off);
            sd += __shfl_xor(sd, off);
        }
        if (ok && (ct & (GRP - 1)) == 0) {
            as_n[(size_t)n * NHEAD + head] = sa;
            ad_n[(size_t)n * NHEAD + head] = sd;
        }
    }
}

// ---------------- fused aggregation: one wave per dst node ----------------
// Per edge: 32B record (p-sequential), 4B as_n gather, h-row gather,
// w = exp(leaky(as+ad+ae)); predicated unroll-8 keeps 8 chains in flight.

template <int C, int AEOFF>
__global__ __launch_bounds__(256) void gat_agg(
    const int* __restrict__ rowptr, const char* __restrict__ rec,
    const __half* __restrict__ hbuf, const float* __restrict__ as_n,
    const float* __restrict__ ad_n, const float* __restrict__ bias,
    float* __restrict__ out) {
    constexpr int FPL = (NHEAD * C) / 64;   // 2 (C=32) or 1 (C=16)
    int lane = threadIdx.x & 63;
    int n = blockIdx.x * 4 + (threadIdx.x >> 6);
    if (n >= N_NODES) return;
    int head = lane >> 4;

    float ad = ad_n[(size_t)n * NHEAD + head];
    const __half2* h2p = reinterpret_cast<const __half2*>(hbuf);

    int p0 = __builtin_amdgcn_readfirstlane(rowptr[n]);
    int p1 = __builtin_amdgcn_readfirstlane(rowptr[n + 1]);

    float acc[8][FPL];
    float den[8];
#pragma unroll
    for (int j = 0; j < 8; ++j) {
        den[j] = 0.f;
#pragma unroll
        for (int k = 0; k < FPL; ++k) acc[j][k] = 0.f;
    }

    for (int p = p0; p < p1; p += 8) {
        int   sp[8];
        float w[8];
#pragma unroll
        for (int j = 0; j < 8; ++j) {
            int pp = p + j;
            bool ok = pp < p1;
            int q = ok ? pp : (p1 - 1);
            const char* rp = rec + (size_t)q * 32;
            sp[j] = *reinterpret_cast<const int*>(rp);
            __half aeh = *reinterpret_cast<const __half*>(rp + AEOFF + 2 * head);
            float a = as_n[(size_t)sp[j] * NHEAD + head] + ad + __half2float(aeh);
            a = (a > 0.f) ? a : 0.2f * a;
            float wv = __expf(a);
            w[j] = ok ? wv : 0.f;
        }
#pragma unroll
        for (int j = 0; j < 8; ++j) {
            float v[FPL];
            if constexpr (C == 32) {
                float2 f = __half22float2(h2p[(size_t)sp[j] * 64 + lane]);
                v[0] = f.x; v[1] = f.y;
            } else {
                v[0] = __half2float(hbuf[(size_t)sp[j] * 64 + lane]);
            }
            den[j] += w[j];
#pragma unroll
            for (int k = 0; k < FPL; ++k) acc[j][k] += w[j] * v[k];
        }
    }

    float dsum = ((den[0] + den[1]) + (den[2] + den[3]))
               + ((den[4] + den[5]) + (den[6] + den[7]));
    float inv = 1.f / (dsum + 1e-16f);
    float v[FPL];
#pragma unroll
    for (int k = 0; k < FPL; ++k) {
        float a = ((acc[0][k] + acc[1][k]) + (acc[2][k] + acc[3][k]))
                + ((acc[4][k] + acc[5][k]) + (acc[6][k] + acc[7][k]));
        v[k] = a * inv;
    }
    // head mean: lanes l, l^16, l^32, l^48 hold the same within-head column
#pragma unroll
    for (int k = 0; k < FPL; ++k) {
        v[k] += __shfl_xor(v[k], 16);
        v[k] += __shfl_xor(v[k], 32);
    }
    if (lane < 16) {
#pragma unroll
        for (int k = 0; k < FPL; ++k) {
            int c = lane * FPL + k;
            float o = 0.25f * v[k] + bias[c];
            o = (o > 0.f) ? o : expm1f(o);
            out[(size_t)n * C + c] = o;
        }
    }
}

// ---------------- launch ----------------

static inline size_t align_up(size_t x, size_t a) { return (x + a - 1) & ~(a - 1); }

extern "C" void kernel_launch(void* const* d_in, const int* in_sizes, int n_in,
                              void* d_out, int out_size, void* d_ws, size_t ws_size,
                              hipStream_t stream) {
    const float* x       = (const float*)d_in[0];
    const int*   ei      = (const int*)d_in[1];
    const float* ea      = (const float*)d_in[2];
    const float* W1      = (const float*)d_in[3];
    const float* We1     = (const float*)d_in[4];
    const float* a_src1  = (const float*)d_in[5];
    const float* a_dst1  = (const float*)d_in[6];
    const float* a_edge1 = (const float*)d_in[7];
    const float* b1      = (const float*)d_in[8];
    const float* W2      = (const float*)d_in[9];
    const float* We2     = (const float*)d_in[10];
    const float* a_src2  = (const float*)d_in[11];
    const float* a_dst2  = (const float*)d_in[12];
    const float* a_edge2 = (const float*)d_in[13];
    const float* b2      = (const float*)d_in[14];
    float* out = (float*)d_out;

    char* p = (char*)d_ws;
    auto take = [&](size_t bytes) { char* r = p; p += align_up(bytes, 256); return r; };
    int*   counts = (int*)take(sizeof(int) * N_NODES);
    int*   rowptr = (int*)take(sizeof(int) * (N_NODES + 1));
    int*   cursor = (int*)take(sizeof(int) * N_NODES);
    int*   bsum   = (int*)take(sizeof(int) * 128);
    char*  rec    = (char*)take((size_t)ETOT * 32);             // 54.4 MB
    float* as_n   = (float*)take(sizeof(float) * N_NODES * NHEAD);
    float* ad_n   = (float*)take(sizeof(float) * N_NODES * NHEAD);
    __half* hbuf  = (__half*)take((size_t)N_NODES * 128 * 2);   // 25.6 MB
    float* x2     = (float*)take(sizeof(float) * (size_t)N_NODES * 32);
    float* M1     = (float*)take(sizeof(float) * ED * NHEAD);
    float* M2     = (float*)take(sizeof(float) * ED * NHEAD);

    hipMemsetAsync(counts, 0, sizeof(int) * N_NODES, stream);

    int egrid = (ETOT + 255) / 256;
    count_kernel<<<egrid, 256, 0, stream>>>(ei, counts);
    scan1_kernel<<<SCAN_NB, SCAN_CHUNK, 0, stream>>>(counts, rowptr, bsum);
    scan2_kernel<<<1, 1, 0, stream>>>(bsum);
    scan3_kernel<<<SCAN_NB, SCAN_CHUNK, 0, stream>>>(rowptr, bsum, cursor);

    make_M<<<1, 32, 0, stream>>>(We1, a_edge1, M1, 32);
    make_M<<<1, 32, 0, stream>>>(We2, a_edge2, M2, 16);

    fill_kernel<<<egrid, 256, 0, stream>>>(ei, ea, M1, M2, cursor, (uint*)rec);

    int ngrid = N_NODES / 4;   // 25000

    // ---- layer 1: Fin=64, C=32 (32 nodes/block), h fp16 ----
    feat_kernel<64, 32><<<(N_NODES + 31) / 32, 256, 0, stream>>>(
        x, W1, a_src1, a_dst1, hbuf, as_n, ad_n);
    gat_agg<32, 4><<<ngrid, 256, 0, stream>>>(rowptr, rec, hbuf, as_n, ad_n, b1, x2);

    // ---- layer 2: Fin=32, C=16 (64 nodes/block), h fp16 ----
    feat_kernel<32, 16><<<(N_NODES + 63) / 64, 256, 0, stream>>>(
        x2, W2, a_src2, a_dst2, hbuf, as_n, ad_n);
    gat_agg<16, 12><<<ngrid, 256, 0, stream>>>(rowptr, rec, hbuf, as_n, ad_n, b2, out);
}